// Round 8
// baseline (395.446 us; speedup 1.0000x reference)
//
#include <hip/hip_runtime.h>
#include <hip/hip_bf16.h>

// ---------------------------------------------------------------------------
// Performer (FAVOR+) attention, MI355X gfx950.  f32 I/O, bf16 MFMA internals.
// R15: favor_out rewritten for 2 barriers/subtile (was 4 + 3 drains):
//   - KX dropped from LDS: GEMM2 B-fragments read 16B direct from global
//     kvxb (L2-resident: 2.9MB total, reused by 8 blocks/bh).
//   - Dsh dropped: denominator broadcast via __shfl(acc2[4][ii], quad*16)
//     (col 64 of the output fragment lives in lane quad*16 of same wave).
//   - Q double-buffered via global_load_lds; Q(s+1) staged during GEMM1(s).
//   LDS: Pj 36864 | Qbuf 2x16384 | qp 75776 = 145408 B.
//   Schedule/subtile: {vmcnt0+bar -> GEMM1 (+issue Q(s+1)) -> epi ->
//   lgkm0+bar -> GEMM2 -> shfl den -> stores}.
// gemm256 (R13-verified, ~920 TF = m97-plateau), favor_kv (R14-verified),
// finalize_kvx2, cvt_x, prep_w all unchanged.
//   prep:  wqkvt(3072x1024)=bf16([Wq|Wk|Wv]^T); wot=bf16(Wo^T); projb padded
//   S1:    [Qb|Kb|Vb](16384x1024 bf16 each) = xb . wqkvt^T   (gemm256 EPI7)
//   favor_kv (grid 64bh x 4slab): kvxT(288x80) += kp . [V;1]^T per 64 rows
//   finalize_kvx2: kvxb[bh][80][288] bf16 = transpose(sum_slab kvp)
//   favor_out (grid 64bh x 8): qp = relu(Q.projb^T)+eps; out = qp.kvxb^T
//       /denom(col 64); merged-head bf16 store
//   S5:    out(f32) = outm . wot^T + bo (gemm256 EPI5)
// Aliases: xb==kvp/kvxb region (dead after S1); outm==Kb (dead after A).
// ---------------------------------------------------------------------------

typedef __bf16 bf16x8 __attribute__((ext_vector_type(8)));
typedef unsigned short u16x8 __attribute__((ext_vector_type(8)));
typedef float  f32x4  __attribute__((ext_vector_type(4)));

#define EPS_F 1e-3f

__device__ __forceinline__ void gld16(const void* g, void* l) {
  __builtin_amdgcn_global_load_lds(
      (const __attribute__((address_space(1))) void*)g,
      (__attribute__((address_space(3))) void*)l, 16, 0, 0);
}

// ---------------------------------------------------------------------------
// gemm256: 256x256 tile, BK=64, 8 waves (2M x 4N), per-wave 128x64 output.
// R13-verified within-wave pipelined K-loop.  Unchanged.
// ---------------------------------------------------------------------------
template <int EPI>
__global__ void __launch_bounds__(512, 2)
gemm256(const __hip_bfloat16* __restrict__ A, long lda,
        const __hip_bfloat16* __restrict__ Bt, long ldb,
        void* __restrict__ Cp, long ldc,
        int Mtiles, int Ntiles, int K, const float* __restrict__ bias) {
  __shared__ __align__(16) char sm[131072];

  const int tid  = threadIdx.x;
  const int lane = tid & 63;
  const int wave = tid >> 6;   // 0..7
  const int wm   = wave >> 2;  // 0..1
  const int wn   = wave & 3;   // 0..3
  const int quad = lane >> 4;
  const int l15  = lane & 15;

  const int bid = blockIdx.x;
  const int Mx  = Mtiles >> 3;
  const int xcd = bid & 7;
  const int wl  = bid >> 3;
  const int gsz = Mx << 2;
  const int grp = wl / gsz;
  const int rr  = wl - grp * gsz;
  const int mt  = xcd * Mx + (rr % Mx);
  const int nt  = (grp << 2) + (rr / Mx);
  const long m0 = (long)mt * 256;
  const long n0 = (long)nt * 256;

  const int srow = tid >> 3;
  const int sg   = (tid & 7) ^ (srow & 7);
  const __hip_bfloat16* aS = A  + (m0 + srow) * lda + sg * 8;
  const __hip_bfloat16* bS = Bt + (n0 + srow) * ldb + sg * 8;
  char* smc = (char*)sm;
  const int ldsOff = tid * 16;

  const int aRowB = (wm * 128 + l15) * 128;
  const int bRowB = 32768 + (wn * 64 + l15) * 128;
  const int sw    = (l15 & 7) << 4;
  const int cx0   = (quad * 16) ^ sw;
  const int cx1   = (64 + quad * 16) ^ sw;

  f32x4 acc[8][4] = {};

#define GLD_A(pp, kk, i)                                                   \
  gld16(aS + (long)(i) * 64 * lda + (kk),                                  \
        smc + (pp) * 65536 + (i) * 8192 + ldsOff);
#define GLD_B(pp, kk, i)                                                   \
  gld16(bS + (long)(i) * 64 * ldb + (kk),                                  \
        smc + (pp) * 65536 + 32768 + (i) * 8192 + ldsOff);

#define QCL(AR, BR, accI, accJ)                                            \
  __builtin_amdgcn_s_setprio(1);                                           \
  _Pragma("unroll") for (int it = 0; it < 4; ++it)                         \
      _Pragma("unroll") for (int jt = 0; jt < 2; ++jt)                     \
          acc[(accI) + it][(accJ) + jt] =                                  \
              __builtin_amdgcn_mfma_f32_16x16x32_bf16(                     \
                  AR[it], BR[jt], acc[(accI) + it][(accJ) + jt], 0, 0, 0); \
  __builtin_amdgcn_s_setprio(0);

  const int NT = K >> 6;
#pragma unroll
  for (int i = 0; i < 4; ++i) { GLD_A(0, 0, i) GLD_B(0, 0, i) }
#pragma unroll
  for (int i = 0; i < 4; ++i) { GLD_A(1, 64, i) GLD_B(1, 64, i) }
  asm volatile("s_waitcnt vmcnt(8)" ::: "memory");
  __builtin_amdgcn_s_barrier();
  asm volatile("" ::: "memory");

  bf16x8 a0k0[4], a1k0[4], a0k1[4], a1k1[4];
  bf16x8 b01k0[2], b23k0[2], b01k1[2], b23k1[2];
#pragma unroll
  for (int jt = 0; jt < 2; ++jt)
    b01k0[jt] = *(const bf16x8*)(smc + bRowB + jt * 2048 + cx0);
#pragma unroll
  for (int it = 0; it < 4; ++it)
    a0k0[it] = *(const bf16x8*)(smc + aRowB + it * 2048 + cx0);

  int p = 0;
  for (int t = 0; t < NT; ++t) {
    const char* base  = smc + p * 65536;
    const char* nbase = smc + (p ^ 1) * 65536;
    const long kk = (long)(t + 2) * 64;
    const bool pf = (t + 2 < NT);

#pragma unroll
    for (int jt = 0; jt < 2; ++jt)
      b23k0[jt] = *(const bf16x8*)(base + bRowB + (jt + 2) * 2048 + cx0);
    QCL(a0k0, b01k0, 0, 0)
#pragma unroll
    for (int it = 0; it < 4; ++it)
      a1k0[it] = *(const bf16x8*)(base + aRowB + (4 + it) * 2048 + cx0);
    QCL(a0k0, b23k0, 0, 2)
#pragma unroll
    for (int jt = 0; jt < 2; ++jt)
      b01k1[jt] = *(const bf16x8*)(base + bRowB + jt * 2048 + cx1);
#pragma unroll
    for (int it = 0; it < 4; ++it)
      a0k1[it] = *(const bf16x8*)(base + aRowB + it * 2048 + cx1);
    QCL(a1k0, b01k0, 4, 0)
#pragma unroll
    for (int jt = 0; jt < 2; ++jt)
      b23k1[jt] = *(const bf16x8*)(base + bRowB + (jt + 2) * 2048 + cx1);
    QCL(a1k0, b23k0, 4, 2)
#pragma unroll
    for (int it = 0; it < 4; ++it)
      a1k1[it] = *(const bf16x8*)(base + aRowB + (4 + it) * 2048 + cx1);
    QCL(a0k1, b01k1, 0, 0)
    QCL(a0k1, b23k1, 0, 2)
    asm volatile("s_waitcnt lgkmcnt(0)" ::: "memory");
    __builtin_amdgcn_s_barrier();
    asm volatile("" ::: "memory");
    if (pf) {
      GLD_A(p, kk, 0) GLD_A(p, kk, 1) GLD_A(p, kk, 2) GLD_A(p, kk, 3)
      GLD_B(p, kk, 0) GLD_B(p, kk, 1) GLD_B(p, kk, 2) GLD_B(p, kk, 3)
    }
    QCL(a1k1, b01k1, 4, 0)
    if (pf) {
      asm volatile("s_waitcnt vmcnt(8)" ::: "memory");
    } else {
      asm volatile("s_waitcnt vmcnt(0)" ::: "memory");
    }
    __builtin_amdgcn_s_barrier();
    asm volatile("" ::: "memory");
    if (t + 1 < NT) {
#pragma unroll
      for (int jt = 0; jt < 2; ++jt)
        b01k0[jt] = *(const bf16x8*)(nbase + bRowB + jt * 2048 + cx0);
#pragma unroll
      for (int it = 0; it < 4; ++it)
        a0k0[it] = *(const bf16x8*)(nbase + aRowB + it * 2048 + cx0);
    }
    QCL(a1k1, b23k1, 4, 2)
    p ^= 1;
  }
#undef GLD_A
#undef GLD_B
#undef QCL

  if constexpr (EPI == 7) {
    __hip_bfloat16* Cb = (__hip_bfloat16*)Cp;
    const long slab  = (n0 >> 10) * 16777216;
    const long ncol0 = (n0 & 1023) + wn * 64 + l15;
#pragma unroll
    for (int it = 0; it < 8; ++it) {
#pragma unroll
      for (int i = 0; i < 4; ++i) {
        const long gm = m0 + wm * 128 + it * 16 + quad * 4 + i;
        __hip_bfloat16* rowp = Cb + slab + gm * 1024 + ncol0;
#pragma unroll
        for (int jt = 0; jt < 4; ++jt)
          rowp[jt * 16] = (__hip_bfloat16)acc[it][jt][i];
      }
    }
  } else if constexpr (EPI == 5) {
    float* Cf = (float*)Cp;
    float bv[4];
#pragma unroll
    for (int jt = 0; jt < 4; ++jt)
      bv[jt] = bias[n0 + wn * 64 + jt * 16 + l15];
#pragma unroll
    for (int it = 0; it < 8; ++it) {
#pragma unroll
      for (int i = 0; i < 4; ++i) {
        const long gm = m0 + wm * 128 + it * 16 + quad * 4 + i;
        float* rowp = Cf + gm * ldc + n0 + wn * 64 + l15;
#pragma unroll
        for (int jt = 0; jt < 4; ++jt)
          rowp[jt * 16] = acc[it][jt][i] + bv[jt];
      }
    }
  }
}

// ---------------------------------------------------------------------------
// favor_kv (R14-verified): KVBLK=64, double-buffered, 1 barrier + 1 vmcnt(0)
// per tile.  Unchanged.
// ---------------------------------------------------------------------------
__global__ void __launch_bounds__(512, 2)
favor_kv(const __hip_bfloat16* __restrict__ Kb,
         const __hip_bfloat16* __restrict__ Vb,
         const __hip_bfloat16* __restrict__ projb_g,
         float* __restrict__ kvp) {
  __shared__ __align__(16) char sm[147456];
  char* Pj  = sm;            // 36864
  char* KtB = sm + 36864;    // 2 x 8192
  char* KPB = sm + 53248;    // 2 x 36864
  char* VTB = sm + 126976;   // 2 x 10240

  const int tid  = threadIdx.x;
  const int lane = tid & 63;
  const int wave = tid >> 6;
  const int quad = lane >> 4;
  const int l15  = lane & 15;
  const int swL  = (l15 & 7) << 4;

  const int bh   = blockIdx.x & 63;
  const int slab = blockIdx.x >> 6;  // 0..3
  const int b    = bh >> 4, h = bh & 15;
  const long rowbase = (long)b * 4096 + (long)slab * 1024;

  for (int p = 0; p < 5; ++p) {
    const int idx = p * 512 + tid;
    if (idx < 2304) {
      const int r = idx >> 3, g = (idx & 7) ^ (r & 7);
      gld16(projb_g + r * 64 + g * 8, Pj + idx * 16);
    }
  }
#pragma unroll
  for (int q = 0; q < 2; ++q) {
    unsigned short* vth = (unsigned short*)(VTB + q * 10240 + 64 * 128);
    for (int i = tid; i < 1024; i += 512) vth[i] = (i < 64) ? 0x3F80 : 0;
  }

  const int rK = tid >> 3, gK = (tid & 7) ^ (rK & 7);
  const int nl = tid >> 3, seg = tid & 7;
  gld16(Kb + (rowbase + rK) * 1024 + h * 64 + gK * 8, KtB + tid * 16);
  u16x8 vc = *(const u16x8*)(Vb + (rowbase + nl) * 1024 + h * 64 + seg * 8);

  const int wm1 = wave & 3;
  const int wn1 = wave >> 2;
  const int nJ  = (wave < 2) ? 3 : 2;

  f32x4 acc2[3][5] = {};

#define KV_GEMM2(KPo, VTo)                                                   \
  _Pragma("unroll") for (int ks = 0; ks < 2; ++ks) {                         \
    const int cb = ks * 64 + quad * 16;                                      \
    bf16x8 bfr2[5];                                                          \
    _Pragma("unroll") for (int fd = 0; fd < 5; ++fd) {                       \
      const int d = fd * 16 + l15;                                           \
      const int s2 = ((d & 7) ^ ((d >> 3) & 7)) << 4;                        \
      bfr2[fd] = *(const bf16x8*)((VTo) + d * 128 + (cb ^ s2));              \
    }                                                                        \
    _Pragma("unroll") for (int j = 0; j < 3; ++j) {                          \
      if (j < nJ) {                                                          \
        const int r2 = (wave + 8 * j) * 16 + l15;                            \
        const bf16x8 af2 =                                                   \
            *(const bf16x8*)((KPo) + r2 * 128 + (cb ^ ((r2 & 7) << 4)));     \
        _Pragma("unroll") for (int fd = 0; fd < 5; ++fd)                     \
            acc2[j][fd] = __builtin_amdgcn_mfma_f32_16x16x32_bf16(           \
                af2, bfr2[fd], acc2[j][fd], 0, 0, 0);                        \
      }                                                                      \
    }                                                                        \
  }

  for (int t = 0; t < 16; ++t) {
    const int q = t & 1;
    char* Kt  = KtB + q * 8192;
    char* KP  = KPB + q * 36864;
    char* VT  = VTB + q * 10240;
    char* KPo = KPB + (q ^ 1) * 36864;
    char* VTo = VTB + (q ^ 1) * 10240;

    asm volatile("s_waitcnt vmcnt(0)" ::: "memory");
    __builtin_amdgcn_s_barrier();
    asm volatile("" ::: "memory");

#pragma unroll
    for (int j = 0; j < 8; ++j) {
      const int d = seg * 8 + j;
      const int s = ((d & 7) ^ ((d >> 3) & 7)) << 4;
      *(unsigned short*)(VT + d * 128 + ((nl * 2) ^ s)) = vc[j];
    }
    if (t < 15) {
      const long nb1 = rowbase + (long)(t + 1) * 64;
      gld16(Kb + (nb1 + rK) * 1024 + h * 64 + gK * 8,
            KtB + (q ^ 1) * 8192 + tid * 16);
      vc = *(const u16x8*)(Vb + (nb1 + nl) * 1024 + h * 64 + seg * 8);
    }
    f32x4 acc1[9] = {};
#pragma unroll
    for (int ks = 0; ks < 2; ++ks) {
      const int cb = ks * 64 + quad * 16;
      const bf16x8 af1 =
          *(const bf16x8*)(Kt + (wm1 * 16 + l15) * 128 + (cb ^ swL));
      bf16x8 bfr[9];
#pragma unroll
      for (int fn = 0; fn < 9; ++fn)
        bfr[fn] = *(const bf16x8*)(Pj + (wn1 * 144 + fn * 16 + l15) * 128 +
                                   (cb ^ swL));
#pragma unroll
      for (int fn = 0; fn < 9; ++fn)
        acc1[fn] = __builtin_amdgcn_mfma_f32_16x16x32_bf16(af1, bfr[fn],
                                                           acc1[fn], 0, 0, 0);
    }
    {
      const int nb = (wm1 * 16 + quad * 4) * 2;
#pragma unroll
      for (int fn = 0; fn < 9; ++fn) {
        const int r = wn1 * 144 + fn * 16 + l15;
        const bool ok = (r < 266);
        union { __hip_bfloat16 hh[4]; uint2 u; } pk;
#pragma unroll
        for (int ii = 0; ii < 4; ++ii) {
          float v = acc1[fn][ii];
          v = ok ? (fmaxf(v, 0.f) + EPS_F) : 0.f;
          pk.hh[ii] = (__hip_bfloat16)v;
        }
        *(uint2*)(KP + r * 128 + (nb ^ ((r & 7) << 4))) = pk.u;
      }
    }
    if (t > 0) { KV_GEMM2(KPo, VTo) }
    asm volatile("s_waitcnt lgkmcnt(0)" ::: "memory");
    __builtin_amdgcn_s_barrier();
    asm volatile("" ::: "memory");
  }
  { KV_GEMM2(KPB + 36864, VTB + 10240) }
#undef KV_GEMM2

  float* dst = kvp + (long)blockIdx.x * 23040;
#pragma unroll
  for (int j = 0; j < 3; ++j) {
    if (j < nJ) {
      const int rb = (wave + 8 * j) * 16 + quad * 4;
#pragma unroll
      for (int fd = 0; fd < 5; ++fd) {
        const int d = fd * 16 + l15;
#pragma unroll
        for (int ii = 0; ii < 4; ++ii)
          dst[(long)(rb + ii) * 80 + d] = acc2[j][fd][ii];
      }
    }
  }
}

// kvxb[bh][d][r] bf16 = sum_slab kvp[slab][bh][r][d]
// 256 blocks = 64 bh x 4 d-quarters (20 d each); padded-LDS transpose.
__global__ void __launch_bounds__(256)
finalize_kvx2(const float* __restrict__ kvp,
              __hip_bfloat16* __restrict__ kvxb) {
  __shared__ float lf[288 * 21];
  const int bh = blockIdx.x >> 2, dq = blockIdx.x & 3, t = threadIdx.x;
  for (int p = 0; p < 23; ++p) {
    const int q = p * 256 + t;
    if (q < 5760) {
      const int r = q / 20, dl = q - r * 20;
      float s = 0.f;
#pragma unroll
      for (int sl = 0; sl < 4; ++sl)
        s += kvp[(long)(sl * 64 + bh) * 23040 + r * 80 + dq * 20 + dl];
      lf[r * 21 + dl] = s;
    }
  }
  __syncthreads();
  for (int p = 0; p < 23; ++p) {
    const int o = p * 256 + t;
    if (o < 5760) {
      const int dl = o / 288, r = o - dl * 288;
      kvxb[(long)bh * 23040 + (long)(dq * 20 + dl) * 288 + r] =
          (__hip_bfloat16)lf[r * 21 + dl];
    }
  }
}

// ---------------------------------------------------------------------------
// favor_out (R15): qp = relu(Q.projb^T)+eps ; out = (qp . kvxb^T)/denom.
// 2 barriers/subtile; KX from global; denominator via __shfl; Q dbuf gld16.
// LDS: Pj[36864] | Qbuf[2][16384] | QP qp[n][592B] (75776) = 145408.
// Race proof: barA(s) separates GEMM2(s-1) qp-reads from epi(s) qp-writes
// and guarantees Q(s) resident (vmcnt 0).  barB(s) makes qp(s) visible and
// proves all waves finished reading Qbuf[q] (GEMM1 precedes epi per-wave).
// Qbuf[q^1] staging during GEMM1(s) is safe: its last readers (GEMM1(s-1))
// finished before barB(s-1) < barA(s).
// ---------------------------------------------------------------------------
__global__ void __launch_bounds__(512, 2)
favor_out(const __hip_bfloat16* __restrict__ Qb,
          const __hip_bfloat16* __restrict__ kvxb_g,
          const __hip_bfloat16* __restrict__ projb_g,
          __hip_bfloat16* __restrict__ outm) {
  __shared__ __align__(16) char sm[145408];
  char* Pj  = sm;            // 36864
  char* QbL = sm + 36864;    // 2 x 16384
  char* QP  = sm + 69632;    // 75776 (qp[n][592B])

  const int tid  = threadIdx.x;
  const int lane = tid & 63;
  const int wave = tid >> 6;
  const int quad = lane >> 4;
  const int l15  = lane & 15;
  const int swL  = (l15 & 7) << 4;

  const int bh  = blockIdx.x >> 3;
  const int rb8 = blockIdx.x & 7;
  const int b = bh >> 4, h = bh & 15;
  const long rowbase = (long)b * 4096 + (long)rb8 * 512;
  const __hip_bfloat16* kx = kvxb_g + (long)bh * 23040;

  // stage projb (pre-swizzled source)
  for (int p = 0; p < 5; ++p) {
    const int idx = p * 512 + tid;
    if (idx < 2304) {
      const int r = idx >> 3, g = (idx & 7) ^ (r & 7);
      gld16(projb_g + r * 64 + g * 8, Pj + idx * 16);
    }
  }
  // Q(0) -> Qbuf[0] (pre-swizzled source, linear LDS dest)
  const int rS = tid >> 3, gS = (tid & 7) ^ (rS & 7);
  const int rS2 = rS + 64, gS2 = (tid & 7) ^ (rS2 & 7);
  gld16(Qb + (rowbase + rS) * 1024 + h * 64 + gS * 8, QbL + tid * 16);
  gld16(Qb + (rowbase + rS2) * 1024 + h * 64 + gS2 * 8, QbL + 8192 + tid * 16);

  const int wm1 = wave >> 2;  // r-base wm1*144 (9 frags)
  const int wn1 = wave & 3;   // n-base wn1*32  (2 frags)

  for (int s = 0; s < 4; ++s) {
    const int q = s & 1;
    const char* Qcur = QbL + q * 16384;
    asm volatile("s_waitcnt vmcnt(0)" ::: "memory");  // Q(s) (+Pj on s==0)
    __builtin_amdgcn_s_barrier();  // also: qp region free (GEMM2(s-1) done)
    asm volatile("" ::: "memory");
    // GEMM1: qp^T = projb-rows x Q-rows
    f32x4 acc1[9][2] = {};
#pragma unroll
    for (int ks = 0; ks < 2; ++ks) {
      const int cb = ks * 64 + quad * 16;
      bf16x8 bfr[2];
#pragma unroll
      for (int fn = 0; fn < 2; ++fn)
        bfr[fn] = *(const bf16x8*)(Qcur + (wn1 * 32 + fn * 16 + l15) * 128 +
                                   (cb ^ swL));
      bf16x8 af[9];
#pragma unroll
      for (int fm = 0; fm < 9; ++fm)
        af[fm] = *(const bf16x8*)(Pj + (wm1 * 144 + fm * 16 + l15) * 128 +
                                  (cb ^ swL));
#pragma unroll
      for (int fm = 0; fm < 9; ++fm)
#pragma unroll
        for (int fn = 0; fn < 2; ++fn)
          acc1[fm][fn] = __builtin_amdgcn_mfma_f32_16x16x32_bf16(
              af[fm], bfr[fn], acc1[fm][fn], 0, 0, 0);
    }
    // stage Q(s+1) into Qbuf[q^1] (safe: last readers ended before barB(s-1))
    if (s < 3) {
      const long n1 = rowbase + (long)(s + 1) * 128;
      gld16(Qb + (n1 + rS) * 1024 + h * 64 + gS * 8,
            QbL + (q ^ 1) * 16384 + tid * 16);
      gld16(Qb + (n1 + rS2) * 1024 + h * 64 + gS2 * 8,
            QbL + (q ^ 1) * 16384 + 8192 + tid * 16);
    }
    // epi: relu+eps (per-element r<266), pack 4 r-consecutive -> QP[n][r]
#pragma unroll
    for (int fm = 0; fm < 9; ++fm) {
      const int r0 = wm1 * 144 + fm * 16 + quad * 4;
#pragma unroll
      for (int fn = 0; fn < 2; ++fn) {
        const int n = wn1 * 32 + fn * 16 + l15;
        union { __hip_bfloat16 hh[4]; uint2 u; } pk;
#pragma unroll
        for (int ii = 0; ii < 4; ++ii) {
          float v = acc1[fm][fn][ii];
          v = (r0 + ii < 266) ? (fmaxf(v, 0.f) + EPS_F) : 0.f;
          pk.hh[ii] = (__hip_bfloat16)v;
        }
        *(uint2*)(QP + n * 592 + r0 * 2) = pk.u;
      }
    }
    asm volatile("s_waitcnt lgkmcnt(0)" ::: "memory");
    __builtin_amdgcn_s_barrier();  // qp visible (all waves past GEMM1)
    asm volatile("" ::: "memory");
    // GEMM2: out(128x80) = qp . kvxb^T ; B-fragments direct from global (L2)
    f32x4 acc2[5] = {};
#pragma unroll
    for (int ks = 0; ks < 9; ++ks) {
      const int cb = ks * 64 + quad * 16;
      const bf16x8 af = *(const bf16x8*)(QP + (wave * 16 + l15) * 592 + cb);
      bf16x8 bfr[5];
#pragma unroll
      for (int fd = 0; fd < 5; ++fd)
        bfr[fd] = *(const bf16x8*)(kx + (fd * 16 + l15) * 288 + ks * 32 +
                                   quad * 8);
#pragma unroll
      for (int fd = 0; fd < 5; ++fd)
        acc2[fd] = __builtin_amdgcn_mfma_f32_16x16x32_bf16(af, bfr[fd],
                                                           acc2[fd], 0, 0, 0);
    }
    // denominator: col 64 = fragment fd=4, lane l15==0 of my quad group
#pragma unroll
    for (int ii = 0; ii < 4; ++ii) {
      const float den = __shfl(acc2[4][ii], quad << 4, 64);
      const float dinv = (den > 1e-30f) ? (1.f / den) : 0.f;
      const int nloc = wave * 16 + quad * 4 + ii;
      __hip_bfloat16* rowp =
          outm + (rowbase + (long)s * 128 + nloc) * 1024 + h * 64;
#pragma unroll
      for (int fd = 0; fd < 4; ++fd)
        rowp[fd * 16 + l15] = (__hip_bfloat16)(acc2[fd][ii] * dinv);
    }
  }
}

// xb = bf16(x), 8 elements/thread
__global__ void cvt_x(const float* __restrict__ x,
                      __hip_bfloat16* __restrict__ xb) {
  const long i = ((long)blockIdx.x * 256 + threadIdx.x) * 8;
  const float4 f0 = *(const float4*)(x + i);
  const float4 f1 = *(const float4*)(x + i + 4);
  union { __hip_bfloat16 h[8]; uint4 u; } r;
  r.h[0] = (__hip_bfloat16)f0.x; r.h[1] = (__hip_bfloat16)f0.y;
  r.h[2] = (__hip_bfloat16)f0.z; r.h[3] = (__hip_bfloat16)f0.w;
  r.h[4] = (__hip_bfloat16)f1.x; r.h[5] = (__hip_bfloat16)f1.y;
  r.h[6] = (__hip_bfloat16)f1.z; r.h[7] = (__hip_bfloat16)f1.w;
  *(uint4*)(xb + i) = r.u;
}

// weight transposes (z=0..3) + projb prep (z=4) in one launch.
__global__ void prep_w(const float* __restrict__ s0,
                       const float* __restrict__ s1,
                       const float* __restrict__ s2,
                       const float* __restrict__ s3,
                       const float* __restrict__ proj,
                       __hip_bfloat16* __restrict__ dq,
                       __hip_bfloat16* __restrict__ dwo,
                       __hip_bfloat16* __restrict__ projb) {
  const int z = blockIdx.z;
  if (z == 4) {
    const int i = (blockIdx.y * 32 + blockIdx.x) * 256 + (int)threadIdx.x;
    if (i < 288 * 64) {
      const int r = i >> 6;
      __hip_bfloat16 v = (__hip_bfloat16)0.f;
      if (r < 266) v = (__hip_bfloat16)proj[i];
      projb[i] = v;
    }
    return;
  }
  __shared__ float t[32][33];
  const float* src = (z == 0) ? s0 : (z == 1) ? s1 : (z == 2) ? s2 : s3;
  __hip_bfloat16* dst = (z < 3) ? (dq + (long)z * 1048576) : dwo;
  const int k0 = blockIdx.x * 32, n0 = blockIdx.y * 32;
  const int tx = threadIdx.x & 31, ty = threadIdx.x >> 5;
#pragma unroll
  for (int i = 0; i < 4; ++i)
    t[ty + i * 8][tx] = src[(long)(k0 + ty + i * 8) * 1024 + n0 + tx];
  __syncthreads();
#pragma unroll
  for (int i = 0; i < 4; ++i)
    dst[(long)(n0 + ty + i * 8) * 1024 + k0 + tx] =
        (__hip_bfloat16)t[tx][ty + i * 8];
}

// ---------------------------------------------------------------------------
extern "C" void kernel_launch(void* const* d_in, const int* in_sizes, int n_in,
                              void* d_out, int out_size, void* d_ws,
                              size_t ws_size, hipStream_t stream) {
  const float* x    = (const float*)d_in[0];
  const float* Wq   = (const float*)d_in[1];
  const float* Wk   = (const float*)d_in[2];
  const float* Wv   = (const float*)d_in[3];
  const float* Wo   = (const float*)d_in[4];
  const float* bo   = (const float*)d_in[5];
  const float* proj = (const float*)d_in[6];
  float* out = (float*)d_out;
  char* ws = (char*)d_ws;

  // ws layout (bytes); total 135,630,848 (proven fit)
  constexpr long o_wqkvt = 0;            // 6,291,456
  constexpr long o_wot   = 6291456;      // 2,097,152
  constexpr long o_projb = 8388608;      // 36,864
  constexpr long o_Qb    = 8425472;      // 33,554,432
  constexpr long o_Kb    = 41979904;     // 33,554,432 (alias outm)
  constexpr long o_Vb    = 75534336;     // 33,554,432
  constexpr long o_xb    = 109088768;    // 33,554,432 (alias kvp/kvxb)
  constexpr long o_kvp   = 109088768;    // 4*64*23040*4 = 23,592,960
  constexpr long o_kvxb  = 132681728;    // 64*23040*2   =  2,949,120

  __hip_bfloat16* wqkvt = (__hip_bfloat16*)(ws + o_wqkvt);
  __hip_bfloat16* wot   = (__hip_bfloat16*)(ws + o_wot);
  __hip_bfloat16* projb = (__hip_bfloat16*)(ws + o_projb);
  __hip_bfloat16* Qb    = (__hip_bfloat16*)(ws + o_Qb);
  __hip_bfloat16* Kb    = (__hip_bfloat16*)(ws + o_Kb);
  __hip_bfloat16* Vb    = (__hip_bfloat16*)(ws + o_Vb);
  __hip_bfloat16* xb    = (__hip_bfloat16*)(ws + o_xb);
  float*          kvp   = (float*)(ws + o_kvp);
  __hip_bfloat16* kvxb  = (__hip_bfloat16*)(ws + o_kvxb);
  __hip_bfloat16* outm  = Kb;  // alias: Kb dead after favor_kv

  // prep
  cvt_x<<<8192, 256, 0, stream>>>(x, xb);
  prep_w<<<dim3(32, 32, 5), 256, 0, stream>>>(Wq, Wk, Wv, Wo, proj, wqkvt,
                                              wot, projb);

  // S1 fused: [Qb|Kb|Vb] = xb . wqkvt^T  (256^2 pipelined GEMM, EPI7)
  gemm256<7><<<768, 512, 0, stream>>>(xb, 1024, wqkvt, 1024, Qb, 0, 64, 12,
                                      1024, nullptr);

  // phase A fused: kvp partials, then reduce+transpose to kvxb
  favor_kv<<<256, 512, 0, stream>>>(Kb, Vb, projb, kvp);
  finalize_kvx2<<<256, 256, 0, stream>>>(kvp, kvxb);

  // phase B fused: outm = (relu(Q.projb^T)+eps) . kvxb^T / denom, merged
  favor_out<<<512, 512, 0, stream>>>(Qb, kvxb, projb, outm);

  // S5: out(f32) = outm . wot^T + bo  (256^2 pipelined GEMM, EPI5)
  gemm256<5><<<256, 512, 0, stream>>>(outm, 1024, wot, 1024, out, 1024, 64, 4,
                                      1024, bo);
}

// Round 9
// 370.889 us; speedup vs baseline: 1.0662x; 1.0662x over previous
//
#include <hip/hip_runtime.h>
#include <hip/hip_bf16.h>

// ---------------------------------------------------------------------------
// Performer (FAVOR+) attention, MI355X gfx950.  f32 I/O, bf16 MFMA internals.
// R16: favor_out = R15 schedule (2 barriers/subtile, shfl denominator,
// separate QP region) with the R15 regression reverted:
//   - KX restored to LDS (staged ONCE per block; R15's per-subtile global
//     gather of kvxb was 8x L2 inflation x4 re-reads -> the 28us regression).
//   - Q fragments read DIRECT from global in GEMM1 (zero intra-block reuse;
//     64B-contiguous per row, L2-resident) -> no Qbuf, no mid-loop vmcnt.
//   LDS: Pj 36864 | KX 47360 | QP 75776 = 160000 (1 block/CU).
// gemm256 (R13-verified ~920 TF), favor_kv (R14-verified), finalize_kvx2,
// cvt_x, prep_w unchanged.
//   prep:  wqkvt(3072x1024)=bf16([Wq|Wk|Wv]^T); wot=bf16(Wo^T); projb padded
//   S1:    [Qb|Kb|Vb](16384x1024 bf16 each) = xb . wqkvt^T   (gemm256 EPI7)
//   favor_kv (grid 64bh x 4slab): kvxT(288x80) += kp . [V;1]^T per 64 rows
//   finalize_kvx2: kvxb[bh][80][288] bf16 = transpose(sum_slab kvp)
//   favor_out (grid 64bh x 8): qp = relu(Q.projb^T)+eps; out = qp.kvxb^T
//       /denom(col 64); merged-head bf16 store
//   S5:    out(f32) = outm . wot^T + bo (gemm256 EPI5)
// Aliases: xb==kvp/kvxb region (dead after S1); outm==Kb (dead after A).
// ---------------------------------------------------------------------------

typedef __bf16 bf16x8 __attribute__((ext_vector_type(8)));
typedef unsigned short u16x8 __attribute__((ext_vector_type(8)));
typedef float  f32x4  __attribute__((ext_vector_type(4)));

#define EPS_F 1e-3f

__device__ __forceinline__ void gld16(const void* g, void* l) {
  __builtin_amdgcn_global_load_lds(
      (const __attribute__((address_space(1))) void*)g,
      (__attribute__((address_space(3))) void*)l, 16, 0, 0);
}

// ---------------------------------------------------------------------------
// gemm256: 256x256 tile, BK=64, 8 waves (2M x 4N), per-wave 128x64 output.
// R13-verified within-wave pipelined K-loop.  Unchanged.
// ---------------------------------------------------------------------------
template <int EPI>
__global__ void __launch_bounds__(512, 2)
gemm256(const __hip_bfloat16* __restrict__ A, long lda,
        const __hip_bfloat16* __restrict__ Bt, long ldb,
        void* __restrict__ Cp, long ldc,
        int Mtiles, int Ntiles, int K, const float* __restrict__ bias) {
  __shared__ __align__(16) char sm[131072];

  const int tid  = threadIdx.x;
  const int lane = tid & 63;
  const int wave = tid >> 6;   // 0..7
  const int wm   = wave >> 2;  // 0..1
  const int wn   = wave & 3;   // 0..3
  const int quad = lane >> 4;
  const int l15  = lane & 15;

  const int bid = blockIdx.x;
  const int Mx  = Mtiles >> 3;
  const int xcd = bid & 7;
  const int wl  = bid >> 3;
  const int gsz = Mx << 2;
  const int grp = wl / gsz;
  const int rr  = wl - grp * gsz;
  const int mt  = xcd * Mx + (rr % Mx);
  const int nt  = (grp << 2) + (rr / Mx);
  const long m0 = (long)mt * 256;
  const long n0 = (long)nt * 256;

  const int srow = tid >> 3;
  const int sg   = (tid & 7) ^ (srow & 7);
  const __hip_bfloat16* aS = A  + (m0 + srow) * lda + sg * 8;
  const __hip_bfloat16* bS = Bt + (n0 + srow) * ldb + sg * 8;
  char* smc = (char*)sm;
  const int ldsOff = tid * 16;

  const int aRowB = (wm * 128 + l15) * 128;
  const int bRowB = 32768 + (wn * 64 + l15) * 128;
  const int sw    = (l15 & 7) << 4;
  const int cx0   = (quad * 16) ^ sw;
  const int cx1   = (64 + quad * 16) ^ sw;

  f32x4 acc[8][4] = {};

#define GLD_A(pp, kk, i)                                                   \
  gld16(aS + (long)(i) * 64 * lda + (kk),                                  \
        smc + (pp) * 65536 + (i) * 8192 + ldsOff);
#define GLD_B(pp, kk, i)                                                   \
  gld16(bS + (long)(i) * 64 * ldb + (kk),                                  \
        smc + (pp) * 65536 + 32768 + (i) * 8192 + ldsOff);

#define QCL(AR, BR, accI, accJ)                                            \
  __builtin_amdgcn_s_setprio(1);                                           \
  _Pragma("unroll") for (int it = 0; it < 4; ++it)                         \
      _Pragma("unroll") for (int jt = 0; jt < 2; ++jt)                     \
          acc[(accI) + it][(accJ) + jt] =                                  \
              __builtin_amdgcn_mfma_f32_16x16x32_bf16(                     \
                  AR[it], BR[jt], acc[(accI) + it][(accJ) + jt], 0, 0, 0); \
  __builtin_amdgcn_s_setprio(0);

  const int NT = K >> 6;
#pragma unroll
  for (int i = 0; i < 4; ++i) { GLD_A(0, 0, i) GLD_B(0, 0, i) }
#pragma unroll
  for (int i = 0; i < 4; ++i) { GLD_A(1, 64, i) GLD_B(1, 64, i) }
  asm volatile("s_waitcnt vmcnt(8)" ::: "memory");
  __builtin_amdgcn_s_barrier();
  asm volatile("" ::: "memory");

  bf16x8 a0k0[4], a1k0[4], a0k1[4], a1k1[4];
  bf16x8 b01k0[2], b23k0[2], b01k1[2], b23k1[2];
#pragma unroll
  for (int jt = 0; jt < 2; ++jt)
    b01k0[jt] = *(const bf16x8*)(smc + bRowB + jt * 2048 + cx0);
#pragma unroll
  for (int it = 0; it < 4; ++it)
    a0k0[it] = *(const bf16x8*)(smc + aRowB + it * 2048 + cx0);

  int p = 0;
  for (int t = 0; t < NT; ++t) {
    const char* base  = smc + p * 65536;
    const char* nbase = smc + (p ^ 1) * 65536;
    const long kk = (long)(t + 2) * 64;
    const bool pf = (t + 2 < NT);

#pragma unroll
    for (int jt = 0; jt < 2; ++jt)
      b23k0[jt] = *(const bf16x8*)(base + bRowB + (jt + 2) * 2048 + cx0);
    QCL(a0k0, b01k0, 0, 0)
#pragma unroll
    for (int it = 0; it < 4; ++it)
      a1k0[it] = *(const bf16x8*)(base + aRowB + (4 + it) * 2048 + cx0);
    QCL(a0k0, b23k0, 0, 2)
#pragma unroll
    for (int jt = 0; jt < 2; ++jt)
      b01k1[jt] = *(const bf16x8*)(base + bRowB + jt * 2048 + cx1);
#pragma unroll
    for (int it = 0; it < 4; ++it)
      a0k1[it] = *(const bf16x8*)(base + aRowB + it * 2048 + cx1);
    QCL(a1k0, b01k0, 4, 0)
#pragma unroll
    for (int jt = 0; jt < 2; ++jt)
      b23k1[jt] = *(const bf16x8*)(base + bRowB + (jt + 2) * 2048 + cx1);
    QCL(a1k0, b23k0, 4, 2)
#pragma unroll
    for (int it = 0; it < 4; ++it)
      a1k1[it] = *(const bf16x8*)(base + aRowB + (4 + it) * 2048 + cx1);
    QCL(a0k1, b01k1, 0, 0)
    QCL(a0k1, b23k1, 0, 2)
    asm volatile("s_waitcnt lgkmcnt(0)" ::: "memory");
    __builtin_amdgcn_s_barrier();
    asm volatile("" ::: "memory");
    if (pf) {
      GLD_A(p, kk, 0) GLD_A(p, kk, 1) GLD_A(p, kk, 2) GLD_A(p, kk, 3)
      GLD_B(p, kk, 0) GLD_B(p, kk, 1) GLD_B(p, kk, 2) GLD_B(p, kk, 3)
    }
    QCL(a1k1, b01k1, 4, 0)
    if (pf) {
      asm volatile("s_waitcnt vmcnt(8)" ::: "memory");
    } else {
      asm volatile("s_waitcnt vmcnt(0)" ::: "memory");
    }
    __builtin_amdgcn_s_barrier();
    asm volatile("" ::: "memory");
    if (t + 1 < NT) {
#pragma unroll
      for (int jt = 0; jt < 2; ++jt)
        b01k0[jt] = *(const bf16x8*)(nbase + bRowB + jt * 2048 + cx0);
#pragma unroll
      for (int it = 0; it < 4; ++it)
        a0k0[it] = *(const bf16x8*)(nbase + aRowB + it * 2048 + cx0);
    }
    QCL(a1k1, b23k1, 4, 2)
    p ^= 1;
  }
#undef GLD_A
#undef GLD_B
#undef QCL

  if constexpr (EPI == 7) {
    __hip_bfloat16* Cb = (__hip_bfloat16*)Cp;
    const long slab  = (n0 >> 10) * 16777216;
    const long ncol0 = (n0 & 1023) + wn * 64 + l15;
#pragma unroll
    for (int it = 0; it < 8; ++it) {
#pragma unroll
      for (int i = 0; i < 4; ++i) {
        const long gm = m0 + wm * 128 + it * 16 + quad * 4 + i;
        __hip_bfloat16* rowp = Cb + slab + gm * 1024 + ncol0;
#pragma unroll
        for (int jt = 0; jt < 4; ++jt)
          rowp[jt * 16] = (__hip_bfloat16)acc[it][jt][i];
      }
    }
  } else if constexpr (EPI == 5) {
    float* Cf = (float*)Cp;
    float bv[4];
#pragma unroll
    for (int jt = 0; jt < 4; ++jt)
      bv[jt] = bias[n0 + wn * 64 + jt * 16 + l15];
#pragma unroll
    for (int it = 0; it < 8; ++it) {
#pragma unroll
      for (int i = 0; i < 4; ++i) {
        const long gm = m0 + wm * 128 + it * 16 + quad * 4 + i;
        float* rowp = Cf + gm * ldc + n0 + wn * 64 + l15;
#pragma unroll
        for (int jt = 0; jt < 4; ++jt)
          rowp[jt * 16] = acc[it][jt][i] + bv[jt];
      }
    }
  }
}

// ---------------------------------------------------------------------------
// favor_kv (R14-verified): KVBLK=64, double-buffered, 1 barrier + 1 vmcnt(0)
// per tile.  Unchanged.
// ---------------------------------------------------------------------------
__global__ void __launch_bounds__(512, 2)
favor_kv(const __hip_bfloat16* __restrict__ Kb,
         const __hip_bfloat16* __restrict__ Vb,
         const __hip_bfloat16* __restrict__ projb_g,
         float* __restrict__ kvp) {
  __shared__ __align__(16) char sm[147456];
  char* Pj  = sm;            // 36864
  char* KtB = sm + 36864;    // 2 x 8192
  char* KPB = sm + 53248;    // 2 x 36864
  char* VTB = sm + 126976;   // 2 x 10240

  const int tid  = threadIdx.x;
  const int lane = tid & 63;
  const int wave = tid >> 6;
  const int quad = lane >> 4;
  const int l15  = lane & 15;
  const int swL  = (l15 & 7) << 4;

  const int bh   = blockIdx.x & 63;
  const int slab = blockIdx.x >> 6;  // 0..3
  const int b    = bh >> 4, h = bh & 15;
  const long rowbase = (long)b * 4096 + (long)slab * 1024;

  for (int p = 0; p < 5; ++p) {
    const int idx = p * 512 + tid;
    if (idx < 2304) {
      const int r = idx >> 3, g = (idx & 7) ^ (r & 7);
      gld16(projb_g + r * 64 + g * 8, Pj + idx * 16);
    }
  }
#pragma unroll
  for (int q = 0; q < 2; ++q) {
    unsigned short* vth = (unsigned short*)(VTB + q * 10240 + 64 * 128);
    for (int i = tid; i < 1024; i += 512) vth[i] = (i < 64) ? 0x3F80 : 0;
  }

  const int rK = tid >> 3, gK = (tid & 7) ^ (rK & 7);
  const int nl = tid >> 3, seg = tid & 7;
  gld16(Kb + (rowbase + rK) * 1024 + h * 64 + gK * 8, KtB + tid * 16);
  u16x8 vc = *(const u16x8*)(Vb + (rowbase + nl) * 1024 + h * 64 + seg * 8);

  const int wm1 = wave & 3;
  const int wn1 = wave >> 2;
  const int nJ  = (wave < 2) ? 3 : 2;

  f32x4 acc2[3][5] = {};

#define KV_GEMM2(KPo, VTo)                                                   \
  _Pragma("unroll") for (int ks = 0; ks < 2; ++ks) {                         \
    const int cb = ks * 64 + quad * 16;                                      \
    bf16x8 bfr2[5];                                                          \
    _Pragma("unroll") for (int fd = 0; fd < 5; ++fd) {                       \
      const int d = fd * 16 + l15;                                           \
      const int s2 = ((d & 7) ^ ((d >> 3) & 7)) << 4;                        \
      bfr2[fd] = *(const bf16x8*)((VTo) + d * 128 + (cb ^ s2));              \
    }                                                                        \
    _Pragma("unroll") for (int j = 0; j < 3; ++j) {                          \
      if (j < nJ) {                                                          \
        const int r2 = (wave + 8 * j) * 16 + l15;                            \
        const bf16x8 af2 =                                                   \
            *(const bf16x8*)((KPo) + r2 * 128 + (cb ^ ((r2 & 7) << 4)));     \
        _Pragma("unroll") for (int fd = 0; fd < 5; ++fd)                     \
            acc2[j][fd] = __builtin_amdgcn_mfma_f32_16x16x32_bf16(           \
                af2, bfr2[fd], acc2[j][fd], 0, 0, 0);                        \
      }                                                                      \
    }                                                                        \
  }

  for (int t = 0; t < 16; ++t) {
    const int q = t & 1;
    char* Kt  = KtB + q * 8192;
    char* KP  = KPB + q * 36864;
    char* VT  = VTB + q * 10240;
    char* KPo = KPB + (q ^ 1) * 36864;
    char* VTo = VTB + (q ^ 1) * 10240;

    asm volatile("s_waitcnt vmcnt(0)" ::: "memory");
    __builtin_amdgcn_s_barrier();
    asm volatile("" ::: "memory");

#pragma unroll
    for (int j = 0; j < 8; ++j) {
      const int d = seg * 8 + j;
      const int s = ((d & 7) ^ ((d >> 3) & 7)) << 4;
      *(unsigned short*)(VT + d * 128 + ((nl * 2) ^ s)) = vc[j];
    }
    if (t < 15) {
      const long nb1 = rowbase + (long)(t + 1) * 64;
      gld16(Kb + (nb1 + rK) * 1024 + h * 64 + gK * 8,
            KtB + (q ^ 1) * 8192 + tid * 16);
      vc = *(const u16x8*)(Vb + (nb1 + nl) * 1024 + h * 64 + seg * 8);
    }
    f32x4 acc1[9] = {};
#pragma unroll
    for (int ks = 0; ks < 2; ++ks) {
      const int cb = ks * 64 + quad * 16;
      const bf16x8 af1 =
          *(const bf16x8*)(Kt + (wm1 * 16 + l15) * 128 + (cb ^ swL));
      bf16x8 bfr[9];
#pragma unroll
      for (int fn = 0; fn < 9; ++fn)
        bfr[fn] = *(const bf16x8*)(Pj + (wn1 * 144 + fn * 16 + l15) * 128 +
                                   (cb ^ swL));
#pragma unroll
      for (int fn = 0; fn < 9; ++fn)
        acc1[fn] = __builtin_amdgcn_mfma_f32_16x16x32_bf16(af1, bfr[fn],
                                                           acc1[fn], 0, 0, 0);
    }
    {
      const int nb = (wm1 * 16 + quad * 4) * 2;
#pragma unroll
      for (int fn = 0; fn < 9; ++fn) {
        const int r = wn1 * 144 + fn * 16 + l15;
        const bool ok = (r < 266);
        union { __hip_bfloat16 hh[4]; uint2 u; } pk;
#pragma unroll
        for (int ii = 0; ii < 4; ++ii) {
          float v = acc1[fn][ii];
          v = ok ? (fmaxf(v, 0.f) + EPS_F) : 0.f;
          pk.hh[ii] = (__hip_bfloat16)v;
        }
        *(uint2*)(KP + r * 128 + (nb ^ ((r & 7) << 4))) = pk.u;
      }
    }
    if (t > 0) { KV_GEMM2(KPo, VTo) }
    asm volatile("s_waitcnt lgkmcnt(0)" ::: "memory");
    __builtin_amdgcn_s_barrier();
    asm volatile("" ::: "memory");
  }
  { KV_GEMM2(KPB + 36864, VTB + 10240) }
#undef KV_GEMM2

  float* dst = kvp + (long)blockIdx.x * 23040;
#pragma unroll
  for (int j = 0; j < 3; ++j) {
    if (j < nJ) {
      const int rb = (wave + 8 * j) * 16 + quad * 4;
#pragma unroll
      for (int fd = 0; fd < 5; ++fd) {
        const int d = fd * 16 + l15;
#pragma unroll
        for (int ii = 0; ii < 4; ++ii)
          dst[(long)(rb + ii) * 80 + d] = acc2[j][fd][ii];
      }
    }
  }
}

// kvxb[bh][d][r] bf16 = sum_slab kvp[slab][bh][r][d]
// 256 blocks = 64 bh x 4 d-quarters (20 d each); padded-LDS transpose.
__global__ void __launch_bounds__(256)
finalize_kvx2(const float* __restrict__ kvp,
              __hip_bfloat16* __restrict__ kvxb) {
  __shared__ float lf[288 * 21];
  const int bh = blockIdx.x >> 2, dq = blockIdx.x & 3, t = threadIdx.x;
  for (int p = 0; p < 23; ++p) {
    const int q = p * 256 + t;
    if (q < 5760) {
      const int r = q / 20, dl = q - r * 20;
      float s = 0.f;
#pragma unroll
      for (int sl = 0; sl < 4; ++sl)
        s += kvp[(long)(sl * 64 + bh) * 23040 + r * 80 + dq * 20 + dl];
      lf[r * 21 + dl] = s;
    }
  }
  __syncthreads();
  for (int p = 0; p < 23; ++p) {
    const int o = p * 256 + t;
    if (o < 5760) {
      const int dl = o / 288, r = o - dl * 288;
      kvxb[(long)bh * 23040 + (long)(dq * 20 + dl) * 288 + r] =
          (__hip_bfloat16)lf[r * 21 + dl];
    }
  }
}

// ---------------------------------------------------------------------------
// favor_out (R16): qp = relu(Q.projb^T)+eps ; out = (qp . kvxb^T)/denom.
// LDS: Pj[36864 swz] | KX[80 x 592B] (staged once) | QP qp[n][592B] = 160000.
// Per subtile: GEMM1 (Q-frags DIRECT from global, Pj LDS) -> epi -> QP ->
// lgkm0+barB -> GEMM2 (QP,KX) -> shfl-denominator -> stores -> barC.
// Race proof: barC(s-1) separates GEMM2(s-1) QP-reads from epi(s) writes;
// barB(s) makes qp(s) visible; Pj/KX read-only after the prologue sync.
// Q-frag loads: 64 lanes cover 16 rows x 64B contiguous -> 2x L2 inflation,
// L2-resident, zero reuse forgone.  Denominator: col 64 = fragment fd=4
// lane quad*16 (l15=0) of the SAME wave -> __shfl, no LDS round-trip.
// ---------------------------------------------------------------------------
__global__ void __launch_bounds__(512, 1)
favor_out(const __hip_bfloat16* __restrict__ Qb,
          const __hip_bfloat16* __restrict__ kvxb_g,
          const __hip_bfloat16* __restrict__ projb_g,
          __hip_bfloat16* __restrict__ outm) {
  __shared__ __align__(16) char sm[160000];
  char* Pj = sm;           // 36864
  char* KX = sm + 36864;   // 47360 (80 x 592B)
  char* QP = sm + 84224;   // 75776 (qp[n][592B])

  const int tid  = threadIdx.x;
  const int lane = tid & 63;
  const int wave = tid >> 6;
  const int quad = lane >> 4;
  const int l15  = lane & 15;
  const int swL  = (l15 & 7) << 4;

  const int bh  = blockIdx.x >> 3;
  const int rb8 = blockIdx.x & 7;
  const int b = bh >> 4, h = bh & 15;
  const long rowbase = (long)b * 4096 + (long)rb8 * 512;

  // stage projb (pre-swizzled source, gld16)
  for (int p = 0; p < 5; ++p) {
    const int idx = p * 512 + tid;
    if (idx < 2304) {
      const int r = idx >> 3, g = (idx & 7) ^ (r & 7);
      gld16(projb_g + r * 64 + g * 8, Pj + idx * 16);
    }
  }
  // stage KX once: kvxb[bh] rows d (288 elems) -> KX[d][592B] (pad unread)
  {
    const __hip_bfloat16* src = kvxb_g + (long)bh * 23040;
#pragma unroll
    for (int p = 0; p < 6; ++p) {
      const int idx = p * 512 + tid;
      if (idx < 2880) {
        const int d = idx / 36, g = idx % 36;
        const bf16x8 v = *(const bf16x8*)(src + d * 288 + g * 8);
        *(bf16x8*)(KX + d * 592 + g * 16) = v;
      }
    }
  }
  __syncthreads();  // Pj (vm) + KX (lgkm) resident; once per kernel

  const int wm1 = wave >> 2;  // r-base wm1*144 (9 frags)
  const int wn1 = wave & 3;   // n-base wn1*32  (2 frags)

  for (int s = 0; s < 4; ++s) {
    const long qrow = rowbase + (long)s * 128;
    // GEMM1: qp^T = projb-rows x Q-rows ; Q fragments direct from global
    f32x4 acc1[9][2] = {};
#pragma unroll
    for (int ks = 0; ks < 2; ++ks) {
      const int cb = ks * 64 + quad * 16;
      bf16x8 bfr[2];
#pragma unroll
      for (int fn = 0; fn < 2; ++fn)
        bfr[fn] = *(const bf16x8*)(Qb +
                                   (qrow + wn1 * 32 + fn * 16 + l15) * 1024 +
                                   h * 64 + ks * 32 + quad * 8);
      bf16x8 af[9];
#pragma unroll
      for (int fm = 0; fm < 9; ++fm)
        af[fm] = *(const bf16x8*)(Pj + (wm1 * 144 + fm * 16 + l15) * 128 +
                                  (cb ^ swL));
#pragma unroll
      for (int fm = 0; fm < 9; ++fm)
#pragma unroll
        for (int fn = 0; fn < 2; ++fn)
          acc1[fm][fn] = __builtin_amdgcn_mfma_f32_16x16x32_bf16(
              af[fm], bfr[fn], acc1[fm][fn], 0, 0, 0);
    }
    // epi: relu+eps (per-element r<266), pack 4 r-consecutive -> QP[n][r]
#pragma unroll
    for (int fm = 0; fm < 9; ++fm) {
      const int r0 = wm1 * 144 + fm * 16 + quad * 4;
#pragma unroll
      for (int fn = 0; fn < 2; ++fn) {
        const int n = wn1 * 32 + fn * 16 + l15;
        union { __hip_bfloat16 hh[4]; uint2 u; } pk;
#pragma unroll
        for (int ii = 0; ii < 4; ++ii) {
          float v = acc1[fm][fn][ii];
          v = (r0 + ii < 266) ? (fmaxf(v, 0.f) + EPS_F) : 0.f;
          pk.hh[ii] = (__hip_bfloat16)v;
        }
        *(uint2*)(QP + n * 592 + r0 * 2) = pk.u;
      }
    }
    asm volatile("s_waitcnt lgkmcnt(0)" ::: "memory");
    __builtin_amdgcn_s_barrier();  // barB: qp(s) visible
    asm volatile("" ::: "memory");
    // GEMM2: out(128x80) = qp . kvxb^T  (K=288, from LDS)
    f32x4 acc2[5] = {};
#pragma unroll
    for (int ks = 0; ks < 9; ++ks) {
      const int cb = ks * 64 + quad * 16;
      const bf16x8 af = *(const bf16x8*)(QP + (wave * 16 + l15) * 592 + cb);
      bf16x8 bfr[5];
#pragma unroll
      for (int fd = 0; fd < 5; ++fd)
        bfr[fd] = *(const bf16x8*)(KX + (fd * 16 + l15) * 592 + cb);
#pragma unroll
      for (int fd = 0; fd < 5; ++fd)
        acc2[fd] = __builtin_amdgcn_mfma_f32_16x16x32_bf16(af, bfr[fd],
                                                           acc2[fd], 0, 0, 0);
    }
    // denominator via in-wave shuffle; store merged-head bf16
#pragma unroll
    for (int ii = 0; ii < 4; ++ii) {
      const float den = __shfl(acc2[4][ii], quad << 4, 64);
      const float dinv = (den > 1e-30f) ? (1.f / den) : 0.f;
      const int nloc = wave * 16 + quad * 4 + ii;
      __hip_bfloat16* rowp = outm + (qrow + nloc) * 1024 + h * 64;
#pragma unroll
      for (int fd = 0; fd < 4; ++fd)
        rowp[fd * 16 + l15] = (__hip_bfloat16)(acc2[fd][ii] * dinv);
    }
    __builtin_amdgcn_s_barrier();  // barC: QP free for next epi
    asm volatile("" ::: "memory");
  }
}

// xb = bf16(x), 8 elements/thread
__global__ void cvt_x(const float* __restrict__ x,
                      __hip_bfloat16* __restrict__ xb) {
  const long i = ((long)blockIdx.x * 256 + threadIdx.x) * 8;
  const float4 f0 = *(const float4*)(x + i);
  const float4 f1 = *(const float4*)(x + i + 4);
  union { __hip_bfloat16 h[8]; uint4 u; } r;
  r.h[0] = (__hip_bfloat16)f0.x; r.h[1] = (__hip_bfloat16)f0.y;
  r.h[2] = (__hip_bfloat16)f0.z; r.h[3] = (__hip_bfloat16)f0.w;
  r.h[4] = (__hip_bfloat16)f1.x; r.h[5] = (__hip_bfloat16)f1.y;
  r.h[6] = (__hip_bfloat16)f1.z; r.h[7] = (__hip_bfloat16)f1.w;
  *(uint4*)(xb + i) = r.u;
}

// weight transposes (z=0..3) + projb prep (z=4) in one launch.
__global__ void prep_w(const float* __restrict__ s0,
                       const float* __restrict__ s1,
                       const float* __restrict__ s2,
                       const float* __restrict__ s3,
                       const float* __restrict__ proj,
                       __hip_bfloat16* __restrict__ dq,
                       __hip_bfloat16* __restrict__ dwo,
                       __hip_bfloat16* __restrict__ projb) {
  const int z = blockIdx.z;
  if (z == 4) {
    const int i = (blockIdx.y * 32 + blockIdx.x) * 256 + (int)threadIdx.x;
    if (i < 288 * 64) {
      const int r = i >> 6;
      __hip_bfloat16 v = (__hip_bfloat16)0.f;
      if (r < 266) v = (__hip_bfloat16)proj[i];
      projb[i] = v;
    }
    return;
  }
  __shared__ float t[32][33];
  const float* src = (z == 0) ? s0 : (z == 1) ? s1 : (z == 2) ? s2 : s3;
  __hip_bfloat16* dst = (z < 3) ? (dq + (long)z * 1048576) : dwo;
  const int k0 = blockIdx.x * 32, n0 = blockIdx.y * 32;
  const int tx = threadIdx.x & 31, ty = threadIdx.x >> 5;
#pragma unroll
  for (int i = 0; i < 4; ++i)
    t[ty + i * 8][tx] = src[(long)(k0 + ty + i * 8) * 1024 + n0 + tx];
  __syncthreads();
#pragma unroll
  for (int i = 0; i < 4; ++i)
    dst[(long)(n0 + ty + i * 8) * 1024 + k0 + tx] =
        (__hip_bfloat16)t[tx][ty + i * 8];
}

// ---------------------------------------------------------------------------
extern "C" void kernel_launch(void* const* d_in, const int* in_sizes, int n_in,
                              void* d_out, int out_size, void* d_ws,
                              size_t ws_size, hipStream_t stream) {
  const float* x    = (const float*)d_in[0];
  const float* Wq   = (const float*)d_in[1];
  const float* Wk   = (const float*)d_in[2];
  const float* Wv   = (const float*)d_in[3];
  const float* Wo   = (const float*)d_in[4];
  const float* bo   = (const float*)d_in[5];
  const float* proj = (const float*)d_in[6];
  float* out = (float*)d_out;
  char* ws = (char*)d_ws;

  // ws layout (bytes); total 135,630,848 (proven fit)
  constexpr long o_wqkvt = 0;            // 6,291,456
  constexpr long o_wot   = 6291456;      // 2,097,152
  constexpr long o_projb = 8388608;      // 36,864
  constexpr long o_Qb    = 8425472;      // 33,554,432
  constexpr long o_Kb    = 41979904;     // 33,554,432 (alias outm)
  constexpr long o_Vb    = 75534336;     // 33,554,432
  constexpr long o_xb    = 109088768;    // 33,554,432 (alias kvp/kvxb)
  constexpr long o_kvp   = 109088768;    // 4*64*23040*4 = 23,592,960
  constexpr long o_kvxb  = 132681728;    // 64*23040*2   =  2,949,120

  __hip_bfloat16* wqkvt = (__hip_bfloat16*)(ws + o_wqkvt);
  __hip_bfloat16* wot   = (__hip_bfloat16*)(ws + o_wot);
  __hip_bfloat16* projb = (__hip_bfloat16*)(ws + o_projb);
  __hip_bfloat16* Qb    = (__hip_bfloat16*)(ws + o_Qb);
  __hip_bfloat16* Kb    = (__hip_bfloat16*)(ws + o_Kb);
  __hip_bfloat16* Vb    = (__hip_bfloat16*)(ws + o_Vb);
  __hip_bfloat16* xb    = (__hip_bfloat16*)(ws + o_xb);
  float*          kvp   = (float*)(ws + o_kvp);
  __hip_bfloat16* kvxb  = (__hip_bfloat16*)(ws + o_kvxb);
  __hip_bfloat16* outm  = Kb;  // alias: Kb dead after favor_kv

  // prep
  cvt_x<<<8192, 256, 0, stream>>>(x, xb);
  prep_w<<<dim3(32, 32, 5), 256, 0, stream>>>(Wq, Wk, Wv, Wo, proj, wqkvt,
                                              wot, projb);

  // S1 fused: [Qb|Kb|Vb] = xb . wqkvt^T  (256^2 pipelined GEMM, EPI7)
  gemm256<7><<<768, 512, 0, stream>>>(xb, 1024, wqkvt, 1024, Qb, 0, 64, 12,
                                      1024, nullptr);

  // phase A fused: kvp partials, then reduce+transpose to kvxb
  favor_kv<<<256, 512, 0, stream>>>(Kb, Vb, projb, kvp);
  finalize_kvx2<<<256, 256, 0, stream>>>(kvp, kvxb);

  // phase B fused: outm = (relu(Q.projb^T)+eps) . kvxb^T / denom, merged
  favor_out<<<512, 512, 0, stream>>>(Qb, kvxb, projb, outm);

  // S5: out(f32) = outm . wot^T + bo  (256^2 pipelined GEMM, EPI5)
  gemm256<5><<<256, 512, 0, stream>>>(outm, 1024, wot, 1024, out, 1024, 64, 4,
                                      1024, bo);
}